// Round 1
// baseline (35109.818 us; speedup 1.0000x reference)
//
#include <hip/hip_runtime.h>
#include <hip/hip_bf16.h>

#define T_LEN 4096
#define HID   512
#define EMB   256
#define KTAG  16
#define START_TAG 14
#define END_TAG   15
#define NEGV  (-10000.0f)
#define NWG   64   // 32 workgroups per direction

// ---------------------------------------------------------------------------
// Device-scope monotonic barrier. All NWG workgroups must call with the same
// sequence of targets. Counter lives in d_ws and is zeroed by hipMemsetAsync
// at the start of every kernel_launch (graph-capture safe, replay safe).
// ---------------------------------------------------------------------------
__device__ __forceinline__ void gbar(unsigned* bar, unsigned target) {
  __syncthreads();   // all waves of this WG done reading/writing
  if (threadIdx.x == 0) {
    __hip_atomic_fetch_add(bar, 1u, __ATOMIC_RELEASE, __HIP_MEMORY_SCOPE_AGENT);
    unsigned guard = 0;
    while (__hip_atomic_load(bar, __ATOMIC_RELAXED, __HIP_MEMORY_SCOPE_AGENT) < target) {
      if (++guard > 10000000u) break;   // safety valve against hangs
    }
  }
  __syncthreads();
  __threadfence();   // acquire: invalidate caches before reading fresh h
}

// ---------------------------------------------------------------------------
// Persistent bidirectional LSTM. 64 WGs x 256 threads, cooperative launch.
// WG (dir, sl) owns h-components J0..J0+15 -> rows {g*512+J0+j} of W_hh/W_ih.
// Each thread holds 128 f32 of W_hh and 64 f32 of W_ih in registers.
// One global barrier per timestep; h double-buffered by step parity.
// ---------------------------------------------------------------------------
__global__ __launch_bounds__(256, 1) void lstm_kernel(
    const float* __restrict__ Whh_f, const float* __restrict__ Whh_b,
    const float* __restrict__ Wih_f, const float* __restrict__ Wih_b,
    const float* __restrict__ b_f,  const float* __restrict__ b_b,
    const float* __restrict__ h0,   const float* __restrict__ c0,
    const int*   __restrict__ x,    const float* __restrict__ embed,
    float* __restrict__ h_state,    // [2 dir][2 parity][512]
    float* __restrict__ hOut,       // [2 dir][T][512]
    unsigned* __restrict__ bar)
{
  const int wg   = blockIdx.x;
  const int dir  = wg >> 5;      // 0 fwd, 1 bwd
  const int sl   = wg & 31;
  const int J0   = sl * 16;
  const int tid  = threadIdx.x;
  const int rloc = tid >> 2;     // 0..63 local row
  const int sub  = tid & 3;      // k-quarter
  const int gate = rloc >> 4;    // 0=i 1=f 2=g 3=o (PyTorch order)
  const int comp = J0 + (rloc & 15);
  const int row  = gate * HID + comp;

  const float* Whh = dir ? Whh_b : Whh_f;
  const float* Wih = dir ? Wih_b : Wih_f;
  const float* bb  = dir ? b_b  : b_f;

  // ---- weights into registers ----
  float w[128];
  {
    const float* wr = Whh + (size_t)row * HID + sub * 128;
    #pragma unroll
    for (int i = 0; i < 32; ++i)
      *(float4*)&w[i*4] = *(const float4*)&wr[i*4];
  }
  float w2[64];
  {
    const float* wr2 = Wih + (size_t)row * EMB + sub * 64;
    #pragma unroll
    for (int i = 0; i < 16; ++i)
      *(float4*)&w2[i*4] = *(const float4*)&wr2[i*4];
  }
  const float bias = bb[row];

  float c = 0.f;
  if (tid < 16) c = c0[dir * HID + J0 + tid];

  // LDS: h staged as 4 segments of 128 words padded to 132 (disjoint bank
  // quads per sub); emb row as 4 segments of 64 words padded to 68.
  __shared__ float hl[4 * 132];
  __shared__ float el[4 * 68];
  __shared__ float gs[64];

  float* hs0 = h_state + dir * 2 * HID;

  // init h_{-1} into parity-1 buffer (one WG per direction)
  if (sl == 0) {
    for (int i = tid; i < HID; i += 256)
      hs0[HID + i] = h0[dir * HID + i];
  }

  // prefetch emb row for first step
  float4 epf = {0.f, 0.f, 0.f, 0.f};
  {
    const int tt0 = dir ? (T_LEN - 1) : 0;
    if (tid < 64)
      epf = *(const float4*)&embed[(size_t)x[tt0] * EMB + tid * 4];
  }

  unsigned bc = 0;
  gbar(bar, ++bc * NWG);   // h0 visible everywhere

  for (int t = 0; t < T_LEN; ++t) {
    const int tt = dir ? (T_LEN - 1 - t) : t;
    const float* hprev = hs0 + ((t & 1) ^ 1) * HID;

    // stage h_{t-1} and emb[tt] into LDS
    if (tid < 128) {
      float4 hv = *(const float4*)&hprev[tid * 4];
      *(float4*)&hl[(tid >> 5) * 132 + (tid & 31) * 4] = hv;
    }
    if (tid < 64) {
      *(float4*)&el[(tid >> 4) * 68 + (tid & 15) * 4] = epf;
    }
    __syncthreads();

    // partial dot: this thread's quarter of row `row`
    float acc = 0.f;
    {
      const float* hseg = hl + sub * 132;
      #pragma unroll
      for (int i = 0; i < 32; ++i) {
        float4 hv = *(const float4*)&hseg[i*4];
        acc += w[i*4+0]*hv.x + w[i*4+1]*hv.y + w[i*4+2]*hv.z + w[i*4+3]*hv.w;
      }
      const float* eseg = el + sub * 68;
      #pragma unroll
      for (int i = 0; i < 16; ++i) {
        float4 ev = *(const float4*)&eseg[i*4];
        acc += w2[i*4+0]*ev.x + w2[i*4+1]*ev.y + w2[i*4+2]*ev.z + w2[i*4+3]*ev.w;
      }
    }
    // reduce the 4 k-quarters (lanes 4r..4r+3)
    acc += __shfl_xor(acc, 1);
    acc += __shfl_xor(acc, 2);
    if (sub == 0) gs[rloc] = acc + bias;
    __syncthreads();

    if (tid < 16) {
      const float gi = gs[tid], gf = gs[16 + tid], gg = gs[32 + tid], go = gs[48 + tid];
      const float si = 1.f / (1.f + expf(-gi));
      const float sf = 1.f / (1.f + expf(-gf));
      const float so = 1.f / (1.f + expf(-go));
      const float cn = sf * c + si * tanhf(gg);
      c = cn;
      const float hv = so * tanhf(cn);
      hs0[(t & 1) * HID + J0 + tid] = hv;
      hOut[((size_t)dir * T_LEN + tt) * HID + J0 + tid] = hv;
    }

    // prefetch next emb row (latency hides under the barrier spin)
    if (t + 1 < T_LEN && tid < 64) {
      const int ttn = dir ? (T_LEN - 2 - t) : (t + 1);
      epf = *(const float4*)&embed[(size_t)x[ttn] * EMB + tid * 4];
    }

    gbar(bar, ++bc * NWG);
  }
}

// ---------------------------------------------------------------------------
// feats[t][k] = concat(hf[t], hb[t]) . fc_w[k] + fc_b[k]
// ---------------------------------------------------------------------------
__global__ __launch_bounds__(256) void feats_kernel(
    const float* __restrict__ hOut, const float* __restrict__ fc_w,
    const float* __restrict__ fc_b, float* __restrict__ feats)
{
  const int tid = threadIdx.x;
  const int k   = tid & 15;
  const int tl  = tid >> 4;
  const int t   = blockIdx.x * 16 + tl;
  const float* hf = hOut + (size_t)t * HID;
  const float* hb = hOut + ((size_t)T_LEN + t) * HID;
  const float* wr = fc_w + (size_t)k * (2 * HID);
  float acc = fc_b[k];
  #pragma unroll 4
  for (int j = 0; j < HID; j += 4) {
    float4 hv = *(const float4*)&hf[j];
    float4 wv = *(const float4*)&wr[j];
    acc += hv.x*wv.x + hv.y*wv.y + hv.z*wv.z + hv.w*wv.w;
  }
  #pragma unroll 4
  for (int j = 0; j < HID; j += 4) {
    float4 hv = *(const float4*)&hb[j];
    float4 wv = *(const float4*)&wr[HID + j];
    acc += hv.x*wv.x + hv.y*wv.y + hv.z*wv.z + hv.w*wv.w;
  }
  feats[(size_t)t * KTAG + k] = acc;
}

// ---------------------------------------------------------------------------
// Viterbi: single block. Wave 0 scans (lane = next*4 + prev_group, first-max
// tie rule preserved), backpointers packed 2-per-byte in LDS. Backtrack via
// per-64-step chunk maps: boundary tags need only 63 sequential lookups.
// ---------------------------------------------------------------------------
__global__ __launch_bounds__(256) void viterbi_kernel(
    const float* __restrict__ feats, const float* __restrict__ trans,
    float* __restrict__ out)
{
  __shared__ float fch[256 * KTAG];           // 16 KB feats chunk
  __shared__ unsigned char bps8[T_LEN * 8];   // 32 KB packed backpointers
  __shared__ float vl[KTAG];
  __shared__ unsigned char ml[64 * 16];       // chunk maps
  __shared__ unsigned char rb[64];            // chunk right-boundary tags
  __shared__ int sbest;

  const int tid  = threadIdx.x;
  const int lane = tid & 63;
  const int nxt  = lane >> 2;
  const int pg   = lane & 3;

  float tr[4];
  if (tid < 64) {
    #pragma unroll
    for (int p = 0; p < 4; ++p)
      tr[p] = trans[nxt * KTAG + pg * 4 + p];
  }
  if (tid < KTAG) vl[tid] = (tid == START_TAG) ? 0.f : NEGV;
  __syncthreads();

  for (int ch = 0; ch < 16; ++ch) {
    // stage 256 timesteps of feats (all 256 threads)
    const float* src = feats + (size_t)ch * 256 * KTAG;
    #pragma unroll
    for (int i = 0; i < 4; ++i)
      *(float4*)&fch[(i * 256 + tid) * 4] = *(const float4*)&src[(i * 256 + tid) * 4];
    __syncthreads();

    if (tid < 64) {
      for (int tl = 0; tl < 256; ++tl) {
        const int t = ch * 256 + tl;
        float best = -3.0e38f; int bp = 0;
        #pragma unroll
        for (int p = 0; p < 4; ++p) {           // ascending p: first-max
          const float sc = vl[pg * 4 + p] + tr[p];
          if (sc > best) { best = sc; bp = pg * 4 + p; }
        }
        #pragma unroll
        for (int m = 1; m <= 2; m <<= 1) {      // merge groups, prefer lower idx
          const float ob = __shfl_xor(best, m);
          const int  obp = __shfl_xor(bp, m);
          if (ob > best || (ob == best && obp < bp)) { best = ob; bp = obp; }
        }
        const int nbp = __shfl(bp, (lane + 4) & 63);  // neighbor next's bp
        if (pg == 0) {
          if ((nxt & 1) == 0)
            bps8[t * 8 + (nxt >> 1)] = (unsigned char)(bp | (nbp << 4));
          vl[nxt] = best + fch[tl * KTAG + nxt];
        }
      }
    }
    __syncthreads();
  }

  // terminal: term[k] = vT[k] + trans[END][k], first-max argmax
  if (tid < 64) {
    float term = (lane < KTAG) ? (vl[lane] + trans[END_TAG * KTAG + lane]) : -3.0e38f;
    int bt = (lane < KTAG) ? lane : KTAG;
    #pragma unroll
    for (int m = 1; m < 64; m <<= 1) {
      const float ot = __shfl_xor(term, m);
      const int  obt = __shfl_xor(bt, m);
      if (ot > term || (ot == term && obt < bt)) { term = ot; bt = obt; }
    }
    if (lane == 0) { out[0] = term; sbest = bt; }
  }
  __syncthreads();

  // chunk maps: lane L composes backpointers over t in [L*64, L*64+63]
  if (tid < 64) {
    const int L = lane;
    unsigned char cur[16];
    #pragma unroll
    for (int g = 0; g < 16; ++g) cur[g] = (unsigned char)g;
    for (int i = 63; i >= 0; --i) {
      const int t = L * 64 + i;
      #pragma unroll
      for (int g = 0; g < 16; ++g) {
        const unsigned char cc = cur[g];
        const unsigned char by = bps8[t * 8 + (cc >> 1)];
        cur[g] = (cc & 1) ? (by >> 4) : (by & 15);
      }
    }
    #pragma unroll
    for (int g = 0; g < 16; ++g) ml[L * 16 + g] = cur[g];
  }
  __syncthreads();

  // boundary tags: 63 sequential single lookups
  if (tid == 0) {
    int r = sbest;
    rb[63] = (unsigned char)r;
    for (int cix = 62; cix >= 0; --cix) {
      r = ml[(cix + 1) * 16 + r];
      rb[cix] = (unsigned char)r;
    }
  }
  __syncthreads();

  // fill paths: lane L walks its chunk from its right boundary
  if (tid < 64) {
    const int L = lane;
    int tag = rb[L];
    out[1 + L * 64 + 63] = (float)tag;
    for (int i = 62; i >= 0; --i) {
      const int t = L * 64 + i + 1;
      const unsigned char by = bps8[t * 8 + (tag >> 1)];
      tag = (tag & 1) ? (by >> 4) : (by & 15);
      out[1 + L * 64 + i] = (float)tag;
    }
  }
}

// ---------------------------------------------------------------------------
extern "C" void kernel_launch(void* const* d_in, const int* in_sizes, int n_in,
                              void* d_out, int out_size, void* d_ws, size_t ws_size,
                              hipStream_t stream) {
  (void)in_sizes; (void)n_in; (void)out_size; (void)ws_size;
  const int*   x      = (const int*)  d_in[0];
  const float* h0     = (const float*)d_in[1];
  const float* c0     = (const float*)d_in[2];
  const float* embed  = (const float*)d_in[3];
  const float* Wih_f  = (const float*)d_in[4];
  const float* Whh_f  = (const float*)d_in[5];
  const float* b_f    = (const float*)d_in[6];
  const float* Wih_b  = (const float*)d_in[7];
  const float* Whh_b  = (const float*)d_in[8];
  const float* b_b    = (const float*)d_in[9];
  const float* fc_w   = (const float*)d_in[10];
  const float* fc_b   = (const float*)d_in[11];
  const float* trans  = (const float*)d_in[12];
  float* out = (float*)d_out;

  char* ws = (char*)d_ws;
  unsigned* bar   = (unsigned*)(ws + 0);            // 1 KB
  float* h_state  = (float*)(ws + 1024);            // 8 KB
  float* feats    = (float*)(ws + 16384);           // 256 KB
  float* hOut     = (float*)(ws + (1ull << 20));    // 16 MB  (total ws ~17 MB)

  hipMemsetAsync(bar, 0, 1024, stream);

  {
    void* args[] = {
      (void*)&Whh_f, (void*)&Whh_b, (void*)&Wih_f, (void*)&Wih_b,
      (void*)&b_f,   (void*)&b_b,   (void*)&h0,    (void*)&c0,
      (void*)&x,     (void*)&embed, (void*)&h_state, (void*)&hOut,
      (void*)&bar
    };
    hipLaunchCooperativeKernel((const void*)lstm_kernel, dim3(NWG), dim3(256),
                               args, 0, stream);
  }

  feats_kernel<<<dim3(T_LEN / 16), 256, 0, stream>>>(hOut, fc_w, fc_b, feats);
  viterbi_kernel<<<dim3(1), 256, 0, stream>>>(feats, trans, out);
}

// Round 2
// 18646.626 us; speedup vs baseline: 1.8829x; 1.8829x over previous
//
#include <hip/hip_runtime.h>
#include <hip/hip_bf16.h>

#define T_LEN 4096
#define HID   512
#define EMB   256
#define KTAG  16
#define START_TAG 14
#define END_TAG   15
#define NEGV  (-10000.0f)
#define NWG   64   // 32 workgroups per direction

// Pack h-value + step tag into one 8B word: a single relaxed agent-scope
// atomic store/load is the whole synchronization protocol (no fences).
__device__ __forceinline__ unsigned long long packph(float h, unsigned tag) {
  return ((unsigned long long)tag << 32) | (unsigned long long)__float_as_uint(h);
}

// ---------------------------------------------------------------------------
// Persistent bidirectional LSTM, barrier-free.
// 64 WGs x 256 threads. Each WAVE is self-contained: owns 4 h-components
// (4 comps x 4 gates = 16 rows, each row split over 4 lanes).
// Per step: poll tagged pairs of h_{t-1} at LLC -> LDS (per-wave copy) ->
// dot -> xor-reduce -> shfl gate gather -> activation -> publish tagged h_t.
// Double buffer by step parity; poll-before-write bounds skew to 1 step.
// ---------------------------------------------------------------------------
__global__ __launch_bounds__(256, 1) void lstm_kernel(
    const float* __restrict__ Whh_f, const float* __restrict__ Whh_b,
    const float* __restrict__ Wih_f, const float* __restrict__ Wih_b,
    const float* __restrict__ b_f,  const float* __restrict__ b_b,
    const float* __restrict__ h0,   const float* __restrict__ c0,
    const int*   __restrict__ x,    const float* __restrict__ embed,
    unsigned long long* __restrict__ pairs,   // [2 dir][2 parity][512]
    float* __restrict__ hOut)                 // [2 dir][T][512]
{
  const int wg   = blockIdx.x;
  const int dir  = wg >> 5;      // 0 fwd, 1 bwd
  const int sl   = wg & 31;
  const int tid  = threadIdx.x;
  const int w    = tid >> 6;     // wave 0..3 (independent)
  const int l    = tid & 63;
  const int gate = l >> 4;       // 0=i 1=f 2=g 3=o
  const int cl   = (l >> 2) & 3; // comp-local 0..3
  const int sub  = l & 3;        // k-quarter
  const int comp = sl * 16 + w * 4 + cl;
  const int row  = gate * HID + comp;

  const float* Whh = dir ? Whh_b : Whh_f;
  const float* Wih = dir ? Wih_b : Wih_f;
  const float* bb  = dir ? b_b  : b_f;

  // weights into registers: this lane's quarter of its row
  float wh[128];
  {
    const float* wr = Whh + (size_t)row * HID + sub * 128;
    #pragma unroll
    for (int i = 0; i < 32; ++i)
      *(float4*)&wh[i*4] = *(const float4*)&wr[i*4];
  }
  float we[64];
  {
    const float* wr2 = Wih + (size_t)row * EMB + sub * 64;
    #pragma unroll
    for (int i = 0; i < 16; ++i)
      *(float4*)&we[i*4] = *(const float4*)&wr2[i*4];
  }
  const float bi = bb[0*HID + comp];
  const float bf = bb[1*HID + comp];
  const float bg = bb[2*HID + comp];
  const float bo = bb[3*HID + comp];

  float c = c0[dir * HID + comp];   // replicated across the comp's 16 lanes

  // per-wave LDS copies (no cross-wave sharing -> no __syncthreads anywhere)
  __shared__ float hl[4][4*132];
  __shared__ float el[4][4*68];
  float* hlw = hl[w];
  float* elw = el[w];

  unsigned long long* pb = pairs + (size_t)dir * 2 * 512;

  // publish h_{-1} (parity 1, tag 1); pairs buffer was memset to 0
  if (gate == 0 && sub == 0) {
    __hip_atomic_store(&pb[512 + comp], packph(h0[dir*HID + comp], 1u),
                       __ATOMIC_RELAXED, __HIP_MEMORY_SCOPE_AGENT);
  }

  // prefetch emb row for step 0 (each wave holds the full 256-f32 row)
  float4 epf;
  {
    const int tt0 = dir ? (T_LEN - 1) : 0;
    epf = *(const float4*)&embed[(size_t)x[tt0] * EMB + l * 4];
  }

  unsigned spins = 0;

  for (int t = 0; t < T_LEN; ++t) {
    const int tt = dir ? (T_LEN - 1 - t) : t;

    // issue first poll round early (in flight during emb work)
    unsigned long long* psrc = pb + (((t & 1) ^ 1) * 512) + l * 8;
    unsigned long long pr[8];
    #pragma unroll
    for (int i = 0; i < 8; ++i)
      pr[i] = __hip_atomic_load(&psrc[i], __ATOMIC_RELAXED, __HIP_MEMORY_SCOPE_AGENT);

    // emb contribution (independent of h) overlaps the poll latency
    *(float4*)&elw[(l >> 4) * 68 + (l & 15) * 4] = epf;
    float acc = 0.f;
    {
      const float* eseg = elw + sub * 68;
      #pragma unroll
      for (int i = 0; i < 16; ++i) {
        float4 ev = *(const float4*)&eseg[i*4];
        acc += we[i*4+0]*ev.x + we[i*4+1]*ev.y + we[i*4+2]*ev.z + we[i*4+3]*ev.w;
      }
    }

    // spin until all 8 of this lane's pairs carry tag t+1 (h_{t-1})
    const unsigned tgt = (unsigned)(t + 1);
    for (;;) {
      bool f = true;
      #pragma unroll
      for (int i = 0; i < 8; ++i) f &= ((unsigned)(pr[i] >> 32) == tgt);
      if (__all(f)) break;
      if (++spins > 4000000u) break;   // safety valve
      #pragma unroll
      for (int i = 0; i < 8; ++i)
        pr[i] = __hip_atomic_load(&psrc[i], __ATOMIC_RELAXED, __HIP_MEMORY_SCOPE_AGENT);
    }

    // polled values -> per-wave LDS copy (words 8l..8l+7 of segment l>>4)
    {
      float* hdst = hlw + (l >> 4) * 132 + (l & 15) * 8;
      float4 a4, b4;
      a4.x = __uint_as_float((unsigned)pr[0]); a4.y = __uint_as_float((unsigned)pr[1]);
      a4.z = __uint_as_float((unsigned)pr[2]); a4.w = __uint_as_float((unsigned)pr[3]);
      b4.x = __uint_as_float((unsigned)pr[4]); b4.y = __uint_as_float((unsigned)pr[5]);
      b4.z = __uint_as_float((unsigned)pr[6]); b4.w = __uint_as_float((unsigned)pr[7]);
      *(float4*)hdst = a4;
      *(float4*)(hdst + 4) = b4;
    }

    // h contribution: 16-lane same-address quads broadcast, conflict-free
    {
      const float* hseg = hlw + sub * 132;
      #pragma unroll
      for (int i = 0; i < 32; ++i) {
        float4 hv = *(const float4*)&hseg[i*4];
        acc += wh[i*4+0]*hv.x + wh[i*4+1]*hv.y + wh[i*4+2]*hv.z + wh[i*4+3]*hv.w;
      }
    }

    // reduce the 4 k-quarters (in-wave, lanes 4r..4r+3)
    acc += __shfl_xor(acc, 1);
    acc += __shfl_xor(acc, 2);

    // gather this comp's 4 gate preactivations (all lanes, redundant)
    const float p0 = __shfl(acc, cl * 4);
    const float p1 = __shfl(acc, cl * 4 + 16);
    const float p2 = __shfl(acc, cl * 4 + 32);
    const float p3 = __shfl(acc, cl * 4 + 48);

    const float gi_ = p0 + bi, gf_ = p1 + bf, gg_ = p2 + bg, go_ = p3 + bo;
    const float si = 1.f / (1.f + expf(-gi_));
    const float sf = 1.f / (1.f + expf(-gf_));
    const float so = 1.f / (1.f + expf(-go_));
    const float cn = sf * c + si * tanhf(gg_);
    c = cn;
    const float hv = so * tanhf(cn);

    // publish h_t immediately (one lane per comp), then the archival store
    if (gate == 0 && sub == 0) {
      __hip_atomic_store(&pb[(t & 1) * 512 + comp], packph(hv, (unsigned)(t + 2)),
                         __ATOMIC_RELAXED, __HIP_MEMORY_SCOPE_AGENT);
      hOut[((size_t)dir * T_LEN + tt) * HID + comp] = hv;
    }

    // prefetch next emb row (hides under next step's poll)
    if (t + 1 < T_LEN) {
      const int ttn = dir ? (T_LEN - 2 - t) : (t + 1);
      epf = *(const float4*)&embed[(size_t)x[ttn] * EMB + l * 4];
    }
  }
}

// ---------------------------------------------------------------------------
// feats[t][k] = concat(hf[t], hb[t]) . fc_w[k] + fc_b[k]
// ---------------------------------------------------------------------------
__global__ __launch_bounds__(256) void feats_kernel(
    const float* __restrict__ hOut, const float* __restrict__ fc_w,
    const float* __restrict__ fc_b, float* __restrict__ feats)
{
  const int tid = threadIdx.x;
  const int k   = tid & 15;
  const int tl  = tid >> 4;
  const int t   = blockIdx.x * 16 + tl;
  const float* hf = hOut + (size_t)t * HID;
  const float* hb = hOut + ((size_t)T_LEN + t) * HID;
  const float* wr = fc_w + (size_t)k * (2 * HID);
  float acc = fc_b[k];
  #pragma unroll 4
  for (int j = 0; j < HID; j += 4) {
    float4 hv = *(const float4*)&hf[j];
    float4 wv = *(const float4*)&wr[j];
    acc += hv.x*wv.x + hv.y*wv.y + hv.z*wv.z + hv.w*wv.w;
  }
  #pragma unroll 4
  for (int j = 0; j < HID; j += 4) {
    float4 hv = *(const float4*)&hb[j];
    float4 wv = *(const float4*)&wr[HID + j];
    acc += hv.x*wv.x + hv.y*wv.y + hv.z*wv.z + hv.w*wv.w;
  }
  feats[(size_t)t * KTAG + k] = acc;
}

// ---------------------------------------------------------------------------
// Viterbi: single block. Wave 0 scans (lane = next*4 + prev_group, first-max
// tie rule preserved), backpointers packed 2-per-byte in LDS. Backtrack via
// per-64-step chunk maps: boundary tags need only 63 sequential lookups.
// ---------------------------------------------------------------------------
__global__ __launch_bounds__(256) void viterbi_kernel(
    const float* __restrict__ feats, const float* __restrict__ trans,
    float* __restrict__ out)
{
  __shared__ float fch[256 * KTAG];           // 16 KB feats chunk
  __shared__ unsigned char bps8[T_LEN * 8];   // 32 KB packed backpointers
  __shared__ float vl[KTAG];
  __shared__ unsigned char ml[64 * 16];       // chunk maps
  __shared__ unsigned char rb[64];            // chunk right-boundary tags
  __shared__ int sbest;

  const int tid  = threadIdx.x;
  const int lane = tid & 63;
  const int nxt  = lane >> 2;
  const int pg   = lane & 3;

  float tr[4];
  if (tid < 64) {
    #pragma unroll
    for (int p = 0; p < 4; ++p)
      tr[p] = trans[nxt * KTAG + pg * 4 + p];
  }
  if (tid < KTAG) vl[tid] = (tid == START_TAG) ? 0.f : NEGV;
  __syncthreads();

  for (int ch = 0; ch < 16; ++ch) {
    const float* src = feats + (size_t)ch * 256 * KTAG;
    #pragma unroll
    for (int i = 0; i < 4; ++i)
      *(float4*)&fch[(i * 256 + tid) * 4] = *(const float4*)&src[(i * 256 + tid) * 4];
    __syncthreads();

    if (tid < 64) {
      for (int tl = 0; tl < 256; ++tl) {
        const int t = ch * 256 + tl;
        float best = -3.0e38f; int bp = 0;
        #pragma unroll
        for (int p = 0; p < 4; ++p) {           // ascending p: first-max
          const float sc = vl[pg * 4 + p] + tr[p];
          if (sc > best) { best = sc; bp = pg * 4 + p; }
        }
        #pragma unroll
        for (int m = 1; m <= 2; m <<= 1) {      // merge groups, prefer lower idx
          const float ob = __shfl_xor(best, m);
          const int  obp = __shfl_xor(bp, m);
          if (ob > best || (ob == best && obp < bp)) { best = ob; bp = obp; }
        }
        const int nbp = __shfl(bp, (lane + 4) & 63);  // neighbor next's bp
        if (pg == 0) {
          if ((nxt & 1) == 0)
            bps8[t * 8 + (nxt >> 1)] = (unsigned char)(bp | (nbp << 4));
          vl[nxt] = best + fch[tl * KTAG + nxt];
        }
      }
    }
    __syncthreads();
  }

  if (tid < 64) {
    float term = (lane < KTAG) ? (vl[lane] + trans[END_TAG * KTAG + lane]) : -3.0e38f;
    int bt = (lane < KTAG) ? lane : KTAG;
    #pragma unroll
    for (int m = 1; m < 64; m <<= 1) {
      const float ot = __shfl_xor(term, m);
      const int  obt = __shfl_xor(bt, m);
      if (ot > term || (ot == term && obt < bt)) { term = ot; bt = obt; }
    }
    if (lane == 0) { out[0] = term; sbest = bt; }
  }
  __syncthreads();

  if (tid < 64) {
    const int L = lane;
    unsigned char cur[16];
    #pragma unroll
    for (int g = 0; g < 16; ++g) cur[g] = (unsigned char)g;
    for (int i = 63; i >= 0; --i) {
      const int t = L * 64 + i;
      #pragma unroll
      for (int g = 0; g < 16; ++g) {
        const unsigned char cc = cur[g];
        const unsigned char by = bps8[t * 8 + (cc >> 1)];
        cur[g] = (cc & 1) ? (by >> 4) : (by & 15);
      }
    }
    #pragma unroll
    for (int g = 0; g < 16; ++g) ml[L * 16 + g] = cur[g];
  }
  __syncthreads();

  if (tid == 0) {
    int r = sbest;
    rb[63] = (unsigned char)r;
    for (int cix = 62; cix >= 0; --cix) {
      r = ml[(cix + 1) * 16 + r];
      rb[cix] = (unsigned char)r;
    }
  }
  __syncthreads();

  if (tid < 64) {
    const int L = lane;
    int tag = rb[L];
    out[1 + L * 64 + 63] = (float)tag;
    for (int i = 62; i >= 0; --i) {
      const int t = L * 64 + i + 1;
      const unsigned char by = bps8[t * 8 + (tag >> 1)];
      tag = (tag & 1) ? (by >> 4) : (by & 15);
      out[1 + L * 64 + i] = (float)tag;
    }
  }
}

// ---------------------------------------------------------------------------
extern "C" void kernel_launch(void* const* d_in, const int* in_sizes, int n_in,
                              void* d_out, int out_size, void* d_ws, size_t ws_size,
                              hipStream_t stream) {
  (void)in_sizes; (void)n_in; (void)out_size; (void)ws_size;
  const int*   x      = (const int*)  d_in[0];
  const float* h0     = (const float*)d_in[1];
  const float* c0     = (const float*)d_in[2];
  const float* embed  = (const float*)d_in[3];
  const float* Wih_f  = (const float*)d_in[4];
  const float* Whh_f  = (const float*)d_in[5];
  const float* b_f    = (const float*)d_in[6];
  const float* Wih_b  = (const float*)d_in[7];
  const float* Whh_b  = (const float*)d_in[8];
  const float* b_b    = (const float*)d_in[9];
  const float* fc_w   = (const float*)d_in[10];
  const float* fc_b   = (const float*)d_in[11];
  const float* trans  = (const float*)d_in[12];
  float* out = (float*)d_out;

  char* ws = (char*)d_ws;
  unsigned long long* pairs = (unsigned long long*)(ws + 0);  // 16 KB
  float* feats    = (float*)(ws + 65536);                     // 256 KB
  float* hOut     = (float*)(ws + (1ull << 20));              // 16 MB

  // zero all tags so stale/poison data can never satisfy a poll
  hipMemsetAsync(pairs, 0, 2 * 2 * 512 * sizeof(unsigned long long), stream);

  {
    void* args[] = {
      (void*)&Whh_f, (void*)&Whh_b, (void*)&Wih_f, (void*)&Wih_b,
      (void*)&b_f,   (void*)&b_b,   (void*)&h0,    (void*)&c0,
      (void*)&x,     (void*)&embed, (void*)&pairs, (void*)&hOut
    };
    hipLaunchCooperativeKernel((const void*)lstm_kernel, dim3(NWG), dim3(256),
                               args, 0, stream);
  }

  feats_kernel<<<dim3(T_LEN / 16), 256, 0, stream>>>(hOut, fc_w, fc_b, feats);
  viterbi_kernel<<<dim3(1), 256, 0, stream>>>(feats, trans, out);
}

// Round 3
// 10469.779 us; speedup vs baseline: 3.3534x; 1.7810x over previous
//
#include <hip/hip_runtime.h>
#include <hip/hip_bf16.h>

#define T_LEN 4096
#define HID   512
#define EMB   256
#define KTAG  16
#define START_TAG 14
#define END_TAG   15
#define NEGV  (-10000.0f)
#define NWG   64   // 32 workgroups per direction

// Pack h-value + step tag into one 8B word: a single relaxed agent-scope
// atomic store/load is the whole synchronization protocol (no fences).
__device__ __forceinline__ unsigned long long packph(float h, unsigned tag) {
  return ((unsigned long long)tag << 32) | (unsigned long long)__float_as_uint(h);
}

// ---------------------------------------------------------------------------
// Persistent bidirectional LSTM, barrier-free across WGs.
// 64 WGs x 256 threads. Wave w of each WG owns k-quarter w of all 64 rows
// (lane = row): it polls ONLY the 128 h-components it consumes (2 pairs per
// lane). Partial sums tree-reduce via parity-double-buffered LDS + one
// __syncthreads per step; wave 0 applies gates and publishes 16 comps as one
// contiguous 128B burst. Poll-before-write bounds cross-WG skew to 1 step.
// ---------------------------------------------------------------------------
__global__ __launch_bounds__(256, 1) void lstm_kernel(
    const float* __restrict__ Whh_f, const float* __restrict__ Whh_b,
    const float* __restrict__ Wih_f, const float* __restrict__ Wih_b,
    const float* __restrict__ b_f,  const float* __restrict__ b_b,
    const float* __restrict__ h0,   const float* __restrict__ c0,
    const int*   __restrict__ x,    const float* __restrict__ embed,
    unsigned long long* __restrict__ pairs,   // [2 dir][2 parity][512]
    float* __restrict__ hOut)                 // [2 dir][T][512]
{
  const int wg   = blockIdx.x;
  const int dir  = wg >> 5;      // 0 fwd, 1 bwd
  const int sl   = wg & 31;
  const int J0   = sl * 16;
  const int tid  = threadIdx.x;
  const int w    = tid >> 6;     // wave 0..3 = k-quarter
  const int l    = tid & 63;     // local row: gate = l>>4, jloc = l&15
  const int jl   = l & 15;
  const int comp = J0 + jl;
  const int grow = (l >> 4) * HID + comp;   // global W row

  const float* Whh = dir ? Whh_b : Whh_f;
  const float* Wih = dir ? Wih_b : Wih_f;
  const float* bb  = dir ? b_b  : b_f;

  // this lane's k-quarter of its row, in registers
  float wh[128];
  {
    const float* wr = Whh + (size_t)grow * HID + w * 128;
    #pragma unroll
    for (int i = 0; i < 32; ++i)
      *(float4*)&wh[i*4] = *(const float4*)&wr[i*4];
  }
  float we[64];
  {
    const float* wr2 = Wih + (size_t)grow * EMB + w * 64;
    #pragma unroll
    for (int i = 0; i < 16; ++i)
      *(float4*)&we[i*4] = *(const float4*)&wr2[i*4];
  }
  const float bi = bb[comp],       bfg = bb[HID + comp];
  const float bg = bb[2*HID + comp], bo = bb[3*HID + comp];
  float c = c0[dir * HID + comp];           // meaningful in wave 0

  __shared__ float hl[4][128];   // per-wave h chunk
  __shared__ float el[4][64];    // per-wave emb quarter
  __shared__ float ps[2][4][64]; // parity-double-buffered partials

  unsigned long long* pb = pairs + (size_t)dir * 2 * 512;

  // publish h_{-1} (parity 1, tag 1); pairs buffer was memset to 0
  if (w == 0 && l < 16)
    __hip_atomic_store(&pb[512 + J0 + l], packph(h0[dir*HID + J0 + l], 1u),
                       __ATOMIC_RELAXED, __HIP_MEMORY_SCOPE_AGENT);

  // prefetch emb quarter for step 0 (scalar per lane, coalesced per wave)
  float epf;
  {
    const int tt0 = dir ? (T_LEN - 1) : 0;
    epf = embed[(size_t)x[tt0] * EMB + w * 64 + l];
  }

  unsigned spins = 0;

  for (int t = 0; t < T_LEN; ++t) {
    const int par = t & 1;
    const int tt  = dir ? (T_LEN - 1 - t) : t;

    // issue this wave's 2-pair poll early (in flight during emb work)
    unsigned long long* psrc = pb + ((par ^ 1) * 512) + w * 128 + 2 * l;
    unsigned long long p0 = __hip_atomic_load(&psrc[0], __ATOMIC_RELAXED, __HIP_MEMORY_SCOPE_AGENT);
    unsigned long long p1 = __hip_atomic_load(&psrc[1], __ATOMIC_RELAXED, __HIP_MEMORY_SCOPE_AGENT);

    // stage emb quarter (intra-wave only: waitcnt + sched fence, no barrier)
    el[w][l] = epf;
    __builtin_amdgcn_wave_barrier();
    asm volatile("s_waitcnt lgkmcnt(0)" ::: "memory");
    __builtin_amdgcn_sched_barrier(0);

    // emb contribution overlaps the poll latency (chain order == round 2)
    float acc = 0.f;
    {
      const float* eseg = el[w];
      #pragma unroll
      for (int i = 0; i < 16; ++i) {
        float4 ev = *(const float4*)&eseg[i*4];
        acc += we[i*4+0]*ev.x + we[i*4+1]*ev.y + we[i*4+2]*ev.z + we[i*4+3]*ev.w;
      }
    }

    // spin until this wave's 128-word chunk carries tag t+1 (h_{t-1})
    const unsigned tgt = (unsigned)(t + 1);
    for (;;) {
      bool f = ((unsigned)(p0 >> 32) == tgt) && ((unsigned)(p1 >> 32) == tgt);
      if (__all(f)) break;
      if (++spins > 2000000u) break;   // safety valve
      __builtin_amdgcn_s_sleep(1);
      p0 = __hip_atomic_load(&psrc[0], __ATOMIC_RELAXED, __HIP_MEMORY_SCOPE_AGENT);
      p1 = __hip_atomic_load(&psrc[1], __ATOMIC_RELAXED, __HIP_MEMORY_SCOPE_AGENT);
    }

    // polled chunk -> per-wave LDS
    {
      float2 hv2;
      hv2.x = __uint_as_float((unsigned)p0);
      hv2.y = __uint_as_float((unsigned)p1);
      *(float2*)&hl[w][2*l] = hv2;
    }
    __builtin_amdgcn_wave_barrier();
    asm volatile("s_waitcnt lgkmcnt(0)" ::: "memory");
    __builtin_amdgcn_sched_barrier(0);

    // h contribution (16-lane same-address reads broadcast, conflict-free)
    {
      const float* hseg = hl[w];
      #pragma unroll
      for (int i = 0; i < 32; ++i) {
        float4 hv = *(const float4*)&hseg[i*4];
        acc += wh[i*4+0]*hv.x + wh[i*4+1]*hv.y + wh[i*4+2]*hv.z + wh[i*4+3]*hv.w;
      }
    }

    ps[par][w][l] = acc;
    __syncthreads();   // the one per-step intra-WG join

    if (w == 0) {
      const float q0 = ps[par][0][l], q1 = ps[par][1][l];
      const float q2 = ps[par][2][l], q3 = ps[par][3][l];
      const float tot = (q0 + q1) + (q2 + q3);   // same tree as round 2
      const float g0 = __shfl(tot, jl);          // gate i row
      const float g1 = __shfl(tot, jl + 16);     // gate f
      const float g2 = __shfl(tot, jl + 32);     // gate g
      const float g3 = __shfl(tot, jl + 48);     // gate o
      const float gi_ = g0 + bi, gf_ = g1 + bfg, gg_ = g2 + bg, go_ = g3 + bo;
      const float si = 1.f / (1.f + expf(-gi_));
      const float sf = 1.f / (1.f + expf(-gf_));
      const float so = 1.f / (1.f + expf(-go_));
      const float cn = sf * c + si * tanhf(gg_);
      c = cn;
      const float hv = so * tanhf(cn);
      if (l < 16) {
        __hip_atomic_store(&pb[par * 512 + J0 + l], packph(hv, (unsigned)(t + 2)),
                           __ATOMIC_RELAXED, __HIP_MEMORY_SCOPE_AGENT);
        hOut[((size_t)dir * T_LEN + tt) * HID + J0 + l] = hv;
      }
    }

    // prefetch next emb quarter (hides under next step's poll)
    if (t + 1 < T_LEN) {
      const int ttn = dir ? (T_LEN - 2 - t) : (t + 1);
      epf = embed[(size_t)x[ttn] * EMB + w * 64 + l];
    }
  }
}

// ---------------------------------------------------------------------------
// feats[t][k] = concat(hf[t], hb[t]) . fc_w[k] + fc_b[k]
// ---------------------------------------------------------------------------
__global__ __launch_bounds__(256) void feats_kernel(
    const float* __restrict__ hOut, const float* __restrict__ fc_w,
    const float* __restrict__ fc_b, float* __restrict__ feats)
{
  const int tid = threadIdx.x;
  const int k   = tid & 15;
  const int tl  = tid >> 4;
  const int t   = blockIdx.x * 16 + tl;
  const float* hf = hOut + (size_t)t * HID;
  const float* hb = hOut + ((size_t)T_LEN + t) * HID;
  const float* wr = fc_w + (size_t)k * (2 * HID);
  float acc = fc_b[k];
  #pragma unroll 4
  for (int j = 0; j < HID; j += 4) {
    float4 hv = *(const float4*)&hf[j];
    float4 wv = *(const float4*)&wr[j];
    acc += hv.x*wv.x + hv.y*wv.y + hv.z*wv.z + hv.w*wv.w;
  }
  #pragma unroll 4
  for (int j = 0; j < HID; j += 4) {
    float4 hv = *(const float4*)&hb[j];
    float4 wv = *(const float4*)&wr[HID + j];
    acc += hv.x*wv.x + hv.y*wv.y + hv.z*wv.z + hv.w*wv.w;
  }
  feats[(size_t)t * KTAG + k] = acc;
}

// ---------------------------------------------------------------------------
// Viterbi: single block. Wave 0 scans (lane = next*4 + prev_group, first-max
// tie rule preserved), backpointers packed 2-per-byte in LDS. Backtrack via
// per-64-step chunk maps: boundary tags need only 63 sequential lookups.
// ---------------------------------------------------------------------------
__global__ __launch_bounds__(256) void viterbi_kernel(
    const float* __restrict__ feats, const float* __restrict__ trans,
    float* __restrict__ out)
{
  __shared__ float fch[256 * KTAG];           // 16 KB feats chunk
  __shared__ unsigned char bps8[T_LEN * 8];   // 32 KB packed backpointers
  __shared__ float vl[KTAG];
  __shared__ unsigned char ml[64 * 16];       // chunk maps
  __shared__ unsigned char rb[64];            // chunk right-boundary tags
  __shared__ int sbest;

  const int tid  = threadIdx.x;
  const int lane = tid & 63;
  const int nxt  = lane >> 2;
  const int pg   = lane & 3;

  float tr[4];
  if (tid < 64) {
    #pragma unroll
    for (int p = 0; p < 4; ++p)
      tr[p] = trans[nxt * KTAG + pg * 4 + p];
  }
  if (tid < KTAG) vl[tid] = (tid == START_TAG) ? 0.f : NEGV;
  __syncthreads();

  for (int ch = 0; ch < 16; ++ch) {
    const float* src = feats + (size_t)ch * 256 * KTAG;
    #pragma unroll
    for (int i = 0; i < 4; ++i)
      *(float4*)&fch[(i * 256 + tid) * 4] = *(const float4*)&src[(i * 256 + tid) * 4];
    __syncthreads();

    if (tid < 64) {
      for (int tl = 0; tl < 256; ++tl) {
        const int t = ch * 256 + tl;
        float best = -3.0e38f; int bp = 0;
        #pragma unroll
        for (int p = 0; p < 4; ++p) {           // ascending p: first-max
          const float sc = vl[pg * 4 + p] + tr[p];
          if (sc > best) { best = sc; bp = pg * 4 + p; }
        }
        #pragma unroll
        for (int m = 1; m <= 2; m <<= 1) {      // merge groups, prefer lower idx
          const float ob = __shfl_xor(best, m);
          const int  obp = __shfl_xor(bp, m);
          if (ob > best || (ob == best && obp < bp)) { best = ob; bp = obp; }
        }
        const int nbp = __shfl(bp, (lane + 4) & 63);  // neighbor next's bp
        if (pg == 0) {
          if ((nxt & 1) == 0)
            bps8[t * 8 + (nxt >> 1)] = (unsigned char)(bp | (nbp << 4));
          vl[nxt] = best + fch[tl * KTAG + nxt];
        }
      }
    }
    __syncthreads();
  }

  if (tid < 64) {
    float term = (lane < KTAG) ? (vl[lane] + trans[END_TAG * KTAG + lane]) : -3.0e38f;
    int bt = (lane < KTAG) ? lane : KTAG;
    #pragma unroll
    for (int m = 1; m < 64; m <<= 1) {
      const float ot = __shfl_xor(term, m);
      const int  obt = __shfl_xor(bt, m);
      if (ot > term || (ot == term && obt < bt)) { term = ot; bt = obt; }
    }
    if (lane == 0) { out[0] = term; sbest = bt; }
  }
  __syncthreads();

  if (tid < 64) {
    const int L = lane;
    unsigned char cur[16];
    #pragma unroll
    for (int g = 0; g < 16; ++g) cur[g] = (unsigned char)g;
    for (int i = 63; i >= 0; --i) {
      const int t = L * 64 + i;
      #pragma unroll
      for (int g = 0; g < 16; ++g) {
        const unsigned char cc = cur[g];
        const unsigned char by = bps8[t * 8 + (cc >> 1)];
        cur[g] = (cc & 1) ? (by >> 4) : (by & 15);
      }
    }
    #pragma unroll
    for (int g = 0; g < 16; ++g) ml[L * 16 + g] = cur[g];
  }
  __syncthreads();

  if (tid == 0) {
    int r = sbest;
    rb[63] = (unsigned char)r;
    for (int cix = 62; cix >= 0; --cix) {
      r = ml[(cix + 1) * 16 + r];
      rb[cix] = (unsigned char)r;
    }
  }
  __syncthreads();

  if (tid < 64) {
    const int L = lane;
    int tag = rb[L];
    out[1 + L * 64 + 63] = (float)tag;
    for (int i = 62; i >= 0; --i) {
      const int t = L * 64 + i + 1;
      const unsigned char by = bps8[t * 8 + (tag >> 1)];
      tag = (tag & 1) ? (by >> 4) : (by & 15);
      out[1 + L * 64 + i] = (float)tag;
    }
  }
}

// ---------------------------------------------------------------------------
extern "C" void kernel_launch(void* const* d_in, const int* in_sizes, int n_in,
                              void* d_out, int out_size, void* d_ws, size_t ws_size,
                              hipStream_t stream) {
  (void)in_sizes; (void)n_in; (void)out_size; (void)ws_size;
  const int*   x      = (const int*)  d_in[0];
  const float* h0     = (const float*)d_in[1];
  const float* c0     = (const float*)d_in[2];
  const float* embed  = (const float*)d_in[3];
  const float* Wih_f  = (const float*)d_in[4];
  const float* Whh_f  = (const float*)d_in[5];
  const float* b_f    = (const float*)d_in[6];
  const float* Wih_b  = (const float*)d_in[7];
  const float* Whh_b  = (const float*)d_in[8];
  const float* b_b    = (const float*)d_in[9];
  const float* fc_w   = (const float*)d_in[10];
  const float* fc_b   = (const float*)d_in[11];
  const float* trans  = (const float*)d_in[12];
  float* out = (float*)d_out;

  char* ws = (char*)d_ws;
  unsigned long long* pairs = (unsigned long long*)(ws + 0);  // 16 KB
  float* feats    = (float*)(ws + 65536);                     // 256 KB
  float* hOut     = (float*)(ws + (1ull << 20));              // 16 MB

  // zero all tags so stale/poison data can never satisfy a poll
  hipMemsetAsync(pairs, 0, 2 * 2 * 512 * sizeof(unsigned long long), stream);

  {
    void* args[] = {
      (void*)&Whh_f, (void*)&Whh_b, (void*)&Wih_f, (void*)&Wih_b,
      (void*)&b_f,   (void*)&b_b,   (void*)&h0,    (void*)&c0,
      (void*)&x,     (void*)&embed, (void*)&pairs, (void*)&hOut
    };
    hipLaunchCooperativeKernel((const void*)lstm_kernel, dim3(NWG), dim3(256),
                               args, 0, stream);
  }

  feats_kernel<<<dim3(T_LEN / 16), 256, 0, stream>>>(hOut, fc_w, fc_b, feats);
  viterbi_kernel<<<dim3(1), 256, 0, stream>>>(feats, trans, out);
}